// Round 1
// baseline (312.990 us; speedup 1.0000x reference)
//
#include <hip/hip_runtime.h>
#include <cstdint>

// ---------------------------------------------------------------------------
// AttentionSelector: selected = softmax(query @ (x@Wk^T+bk)^T) @ x
// x[65536][66] f32, query[8192][66] f32, Wk[66][66] f32, bk[66] f32
// out[8192][66] f32
//
// Strategy: bf16 MFMA (32x32x16) flash-style, NO row-max (scores bounded <<88
// so exp2 never overflows fp32), denominator via ones-column in x^T, split-N
// partials + combine.
// ---------------------------------------------------------------------------

typedef __bf16 bf16x4 __attribute__((ext_vector_type(4)));
typedef __bf16 bf16x8 __attribute__((ext_vector_type(8)));
typedef float  f32x16 __attribute__((ext_vector_type(16)));

extern "C" __device__ float __ocml_native_exp2_f32(float);

#define NUM_PAIRS   65536
#define NUM_Q       8192
#define DIM         66
#define KPITCH      84      // Kb row pitch (bf16): 168B rows -> 2-way-free b64 LDS reads
#define QPITCH      80      // Qb row pitch
#define XROWS       96      // xT rows: 0..65 data, 66 ones, 67..95 zero
#define XPITCH      36      // xT blocked tile col pitch (72B rows)
#define XTILE       (XROWS*XPITCH)        // 3456 elems / 6912 B per 32-pair block
#define PPITCH      68      // P LDS pitch (136B rows, 2-way free)
#define PARTP       68      // partial row pitch (floats)

// LDS map for flash kernel (bytes):
//   Kt:  [64][84] bf16           = 10752   @ 0
//   Xt:  [2][96][36] bf16        = 13824   @ 10752
//   Pt:  [4 waves][64][68] bf16  = 34816   @ 24576
#define LDS_KT 0
#define LDS_XT 10752
#define LDS_PT 24576
#define LDS_TOTAL 59392
#define STAGE_BYTES 24576   // Kt+Xt staged per iter = 24 x 1KB chunks

__device__ __forceinline__ bf16x8 frag8(const __bf16* p) {
    bf16x4 lo = *(const bf16x4*)p;
    bf16x4 hi = *(const bf16x4*)(p + 4);
    return __builtin_shufflevector(lo, hi, 0, 1, 2, 3, 4, 5, 6, 7);
}

__device__ __forceinline__ f32x16 mfma_bf16(bf16x8 a, bf16x8 b, f32x16 c) {
    return __builtin_amdgcn_mfma_f32_32x32x16_bf16(a, b, c, 0, 0, 0);
}

// ---------------------------------------------------------------------------
// Prep A: K = x@Wk^T + bk -> Kb bf16 [n][84] (cols 66..83 = 0)
//         x -> blocked transposed Xb bf16 [n/32][96][36]; row 66 = 1.0
// one block per 32 pair-rows
// ---------------------------------------------------------------------------
__global__ __launch_bounds__(256) void prepA_kernel(
    const float* __restrict__ x, const float* __restrict__ Wk,
    const float* __restrict__ bk,
    unsigned short* __restrict__ Kb_u, unsigned short* __restrict__ Xb_u) {
    __bf16* Kb = (__bf16*)Kb_u;
    __bf16* Xb = (__bf16*)Xb_u;
    __shared__ float sW[DIM * DIM];
    __shared__ float sx[32 * DIM];
    const int tid = threadIdx.x;
    const int n0 = blockIdx.x * 32;

    for (int i = tid; i < DIM * DIM; i += 256) sW[i] = Wk[i];
    for (int i = tid; i < 32 * DIM; i += 256) sx[i] = x[(long)n0 * DIM + i];
    __syncthreads();

    for (int i = tid; i < 32 * KPITCH; i += 256) {
        int r = i / KPITCH, c = i % KPITCH;
        float acc = 0.f;
        if (c < DIM) {
            acc = bk[c];
            const float* xr = &sx[r * DIM];
            const float* wr = &sW[c * DIM];
            #pragma unroll 6
            for (int d = 0; d < DIM; ++d) acc += xr[d] * wr[d];
        }
        Kb[(long)(n0 + r) * KPITCH + c] = (__bf16)acc;
    }
    for (int i = tid; i < XTILE; i += 256) {
        int dd = i / XPITCH, j = i % XPITCH;
        float v = 0.f;
        if (j < 32) v = (dd < DIM) ? sx[j * DIM + dd] : (dd == DIM ? 1.f : 0.f);
        Xb[(long)blockIdx.x * XTILE + i] = (__bf16)v;
    }
}

// ---------------------------------------------------------------------------
// Prep B: Qb bf16 [q][80] = query * log2(e), d-padded with 0
// ---------------------------------------------------------------------------
__global__ __launch_bounds__(256) void prepB_kernel(
    const float* __restrict__ query, unsigned short* __restrict__ Qb_u) {
    __bf16* Qb = (__bf16*)Qb_u;
    int idx = blockIdx.x * 256 + threadIdx.x;       // < 8192*80
    int q = idx / QPITCH, c = idx % QPITCH;
    float v = (c < DIM) ? query[(long)q * DIM + c] * 1.4426950408889634f : 0.f;
    Qb[idx] = (__bf16)v;
}

// ---------------------------------------------------------------------------
// Flash kernel: grid = 32 qblocks * NS chunks; block = 256 thr = 4 waves.
// Wave handles 64 queries (2 mtiles of 32); block iterates its pair chunk in
// tiles of 64 pairs staged to LDS via global_load_lds.
// S = Q K^T (mfma 32x32x16, Kdim 80), P = exp2(S) -> LDS, O += P [X|1].
// ---------------------------------------------------------------------------
__global__ __launch_bounds__(256, 2) void flash_kernel(
    const unsigned short* __restrict__ Qb_u, const unsigned short* __restrict__ Kb_u,
    const unsigned short* __restrict__ Xb_u, float* __restrict__ Part, int NS) {
    __shared__ __attribute__((aligned(16))) char smem[LDS_TOTAL];
    __bf16* Kt = (__bf16*)(smem + LDS_KT);
    __bf16* Xt = (__bf16*)(smem + LDS_XT);
    __bf16* Pt = (__bf16*)(smem + LDS_PT);
    const __bf16* Qb = (const __bf16*)Qb_u;
    const __bf16* Kb = (const __bf16*)Kb_u;
    const __bf16* Xb = (const __bf16*)Xb_u;

    const int tid = threadIdx.x;
    const int lane = tid & 63, wave = tid >> 6;
    const int l31 = lane & 31, h = lane >> 5;
    const int qb = blockIdx.x / NS, ns = blockIdx.x % NS;
    const int ppc = NUM_PAIRS / NS;          // pairs per chunk (multiple of 64)
    const int iters = ppc >> 6;
    const int qbase = qb * 256 + wave * 64;

    // Q A-frags: persistent in registers. A[m=lane&31][k=(lane>>5)*8+j]
    bf16x8 aQ[2][5];
    #pragma unroll
    for (int mt = 0; mt < 2; ++mt)
        #pragma unroll
        for (int kk = 0; kk < 5; ++kk)
            aQ[mt][kk] = *(const bf16x8*)&Qb[(long)(qbase + mt * 32 + l31) * QPITCH + kk * 16 + h * 8];

    f32x16 o[2][3] = {};                      // O accumulators: 2 mtiles x 3 dtiles
    __bf16* Pw = Pt + wave * (64 * PPITCH);   // this wave's private P tile

    for (int it = 0; it < iters; ++it) {
        const long p0 = (long)ns * ppc + (long)it * 64;
        __syncthreads();                      // prev-iter LDS reads done everywhere
        {   // stage Kt (10752B) + Xt (13824B) = 24 chunks of 1KB, lane-contiguous
            const char* gK = (const char*)(Kb + p0 * KPITCH);
            const char* gX = (const char*)(Xb + (p0 >> 5) * XTILE);
            for (int c = wave; c < 24; c += 4) {
                int off = c * 1024 + lane * 16;
                const char* src = (off < 10752) ? (gK + off) : (gX + (off - 10752));
                __builtin_amdgcn_global_load_lds(
                    (const __attribute__((address_space(1))) void*)(uintptr_t)src,
                    (__attribute__((address_space(3))) void*)(unsigned int)(uintptr_t)(smem + c * 1024),
                    16, 0, 0);
            }
        }
        __syncthreads();                      // drains vmcnt: staged tiles visible

        // ---- S = Q K^T over 2 pair-subtiles of 32; P = exp2(S) -> LDS ----
        #pragma unroll
        for (int nt = 0; nt < 2; ++nt) {
            f32x16 s0 = {}, s1 = {};
            #pragma unroll
            for (int kk = 0; kk < 5; ++kk) {
                bf16x8 bK = frag8(&Kt[(nt * 32 + l31) * KPITCH + kk * 16 + h * 8]);
                s0 = mfma_bf16(aQ[0][kk], bK, s0);
                s1 = mfma_bf16(aQ[1][kk], bK, s1);
            }
            // C layout: col=lane&31, row=(reg&3)+8*(reg>>2)+4*(lane>>5)
            #pragma unroll
            for (int r = 0; r < 16; ++r) {
                int row = (r & 3) + 8 * (r >> 2) + 4 * h;
                Pw[(row) * PPITCH + nt * 32 + l31]      = (__bf16)__ocml_native_exp2_f32(s0[r]);
                Pw[(32 + row) * PPITCH + nt * 32 + l31] = (__bf16)__ocml_native_exp2_f32(s1[r]);
            }
        }
        // own-wave LDS RAW (P write -> P read): compiler inserts lgkmcnt wait.

        // ---- O += P @ [X | 1]: 4 ksteps of 16 pairs, 3 dtiles of 32 ----
        #pragma unroll
        for (int ks = 0; ks < 4; ++ks) {
            bf16x8 aP0 = frag8(&Pw[(l31) * PPITCH + ks * 16 + h * 8]);
            bf16x8 aP1 = frag8(&Pw[(32 + l31) * PPITCH + ks * 16 + h * 8]);
            const int pb = ks >> 1, kc = (ks & 1) * 16 + h * 8;
            #pragma unroll
            for (int dt = 0; dt < 3; ++dt) {
                bf16x8 bX = frag8(&Xt[pb * XTILE + (dt * 32 + l31) * XPITCH + kc]);
                o[0][dt] = mfma_bf16(aP0, bX, o[0][dt]);
                o[1][dt] = mfma_bf16(aP1, bX, o[1][dt]);
            }
        }
    }

    // epilogue: write unnormalized partials; col 66 = sum(exp) denominator
    float* dst = Part + (long)ns * NUM_Q * PARTP;
    #pragma unroll
    for (int mt = 0; mt < 2; ++mt)
        #pragma unroll
        for (int dt = 0; dt < 3; ++dt)
            #pragma unroll
            for (int r = 0; r < 16; ++r) {
                int row = (r & 3) + 8 * (r >> 2) + 4 * h;
                int q = qbase + mt * 32 + row;
                int d = dt * 32 + l31;
                if (d < DIM + 1) dst[(long)q * PARTP + d] = o[mt][dt][r];
            }
}

// ---------------------------------------------------------------------------
// Combine: out[q][d] = sum_ns Part[ns][q][d] / sum_ns Part[ns][q][66]
// grid 4096 x 256 (2 queries per block)
// ---------------------------------------------------------------------------
__global__ __launch_bounds__(256) void combine_kernel(
    const float* __restrict__ Part, float* __restrict__ out, int NS) {
    int q = blockIdx.x * 2 + (threadIdx.x >> 7);
    int d = threadIdx.x & 127;
    if (d >= DIM) return;
    float num = 0.f, den = 0.f;
    for (int s = 0; s < NS; ++s) {
        const float* p = Part + ((long)s * NUM_Q + q) * PARTP;
        num += p[d];
        den += p[DIM];
    }
    out[(long)q * DIM + d] = num / den;
}

// ---------------------------------------------------------------------------
// Workspace layout (bytes):
//   Qb   @ 0          : 8192*80*2        = 1,310,720
//   Kb   @ 1310720    : 65536*84*2       = 11,010,048
//   Xb   @ 12320768   : 2048*3456*2      = 14,155,776
//   Part @ 26476544   : NS*8192*68*4
// ---------------------------------------------------------------------------
extern "C" void kernel_launch(void* const* d_in, const int* in_sizes, int n_in,
                              void* d_out, int out_size, void* d_ws, size_t ws_size,
                              hipStream_t stream) {
    const float* x     = (const float*)d_in[0];
    const float* query = (const float*)d_in[1];
    const float* Wk    = (const float*)d_in[2];
    const float* bk    = (const float*)d_in[3];
    float* out = (float*)d_out;
    char* ws = (char*)d_ws;

    unsigned short* Qb = (unsigned short*)(ws + 0);
    unsigned short* Kb = (unsigned short*)(ws + 1310720);
    unsigned short* Xb = (unsigned short*)(ws + 12320768);
    float* Part        = (float*)(ws + 26476544);

    int NS = 16;
    while (NS > 1 &&
           26476544ULL + (unsigned long long)NS * NUM_Q * PARTP * 4ULL > (unsigned long long)ws_size)
        NS >>= 1;

    prepA_kernel<<<NUM_PAIRS / 32, 256, 0, stream>>>(x, Wk, bk, Kb, Xb);
    prepB_kernel<<<(NUM_Q * QPITCH) / 256, 256, 0, stream>>>(query, Qb);
    flash_kernel<<<(NUM_Q / 256) * NS, 256, 0, stream>>>(Qb, Kb, Xb, Part, NS);
    combine_kernel<<<NUM_Q / 2, 256, 0, stream>>>(Part, out, NS);
}

// Round 2
// 290.735 us; speedup vs baseline: 1.0765x; 1.0765x over previous
//
#include <hip/hip_runtime.h>
#include <cstdint>

// ---------------------------------------------------------------------------
// AttentionSelector: selected = softmax(query @ (x@Wk^T+bk)^T) @ x
// R2: (a) S computed TRANSPOSED (Sᵀ=K·Qᵀ) so P exits mfma in C-layout that is
//     two v_permlane32_swap_b32 away from the PV A-operand layout — the P
//     LDS round-trip (64 ds_write_b16 + 16 ds_read_b64 + RAW drain per
//     wave-iter) is gone; LDS 59392 -> 24576 B.
//     (b) Q/K in f16 (same MFMA rate, ~8x more accurate scores; P/X stay bf16
//     since P can exceed f16 max).
//     (c) prepA rebuilt on mfma f16 (old scalar version was LDS-bound ~96us).
// ---------------------------------------------------------------------------

typedef __bf16    bf16x4 __attribute__((ext_vector_type(4)));
typedef __bf16    bf16x8 __attribute__((ext_vector_type(8)));
typedef _Float16  f16x4  __attribute__((ext_vector_type(4)));
typedef _Float16  f16x8  __attribute__((ext_vector_type(8)));
typedef float     f32x16 __attribute__((ext_vector_type(16)));

extern "C" __device__ float __ocml_native_exp2_f32(float);

#define NUM_PAIRS   65536
#define NUM_Q       8192
#define DIM         66
#define KPITCH      84      // Kh row pitch (f16): 168B rows
#define QPITCH      80      // Qh row pitch (f16)
#define XROWS       96      // xT rows: 0..65 data, 66 ones, 67..95 zero
#define XPITCH      36      // xT blocked tile col pitch (72B rows)
#define XTILE       (XROWS*XPITCH)        // 3456 elems / 6912 B per 32-pair block
#define PARTP       68      // partial row pitch (floats)

// flash LDS map (bytes): Kt [64][84] f16 = 10752 @0 ; Xt [2][96][36] bf16 = 13824 @10752
#define LDS_KT 0
#define LDS_XT 10752
#define LDS_TOTAL 24576     // = 24 chunks of 1KB staged per iter

__device__ __forceinline__ bf16x8 frag8(const __bf16* p) {
    bf16x4 lo = *(const bf16x4*)p;
    bf16x4 hi = *(const bf16x4*)(p + 4);
    return __builtin_shufflevector(lo, hi, 0, 1, 2, 3, 4, 5, 6, 7);
}
__device__ __forceinline__ f16x8 frag8h(const _Float16* p) {
    f16x4 lo = *(const f16x4*)p;
    f16x4 hi = *(const f16x4*)(p + 4);
    return __builtin_shufflevector(lo, hi, 0, 1, 2, 3, 4, 5, 6, 7);
}
__device__ __forceinline__ f32x16 mfma_bf16(bf16x8 a, bf16x8 b, f32x16 c) {
    return __builtin_amdgcn_mfma_f32_32x32x16_bf16(a, b, c, 0, 0, 0);
}
__device__ __forceinline__ f32x16 mfma_f16(f16x8 a, f16x8 b, f32x16 c) {
    return __builtin_amdgcn_mfma_f32_32x32x16_f16(a, b, c, 0, 0, 0);
}

// gfx950: exchange lanes 32..63 of a with lanes 0..31 of b.
__device__ __forceinline__ void plswap(unsigned &a, unsigned &b) {
    asm("v_permlane32_swap_b32 %0, %1" : "+v"(a), "+v"(b));
}

__device__ __forceinline__ unsigned packbf(float a, float b) {
    union { __bf16 h[2]; unsigned u; } t;
    t.h[0] = (__bf16)a; t.h[1] = (__bf16)b;
    return t.u;
}

union U4 { unsigned u[4]; bf16x8 v; };

// Sᵀ C-tile (16 f32, col=query l31, row(pair lr)=(r&3)+8*(r>>2)+4h) ->
// exp2 -> two PV A-frags (parity 0: pairs 0..15, parity 1: pairs 16..31).
// A-frag needs lane(l31,h) to hold pairs 16*par+8h+0..7; C-regs hold lr
// {0-3,8-11,16-19,24-27}+4h. Pack adjacent regs to bf16x2, then
// permlane32_swap(E0,F0),(E1,F1) rearranges across the h-halves exactly.
__device__ __forceinline__ void makefrags(const f32x16 &s, U4 *f) {
    float P[16];
    #pragma unroll
    for (int r = 0; r < 16; ++r) P[r] = __ocml_native_exp2_f32(s[r]);
    unsigned E0 = packbf(P[0],  P[1]),  E1 = packbf(P[2],  P[3]);
    unsigned F0 = packbf(P[4],  P[5]),  F1 = packbf(P[6],  P[7]);
    plswap(E0, F0); plswap(E1, F1);
    f[0].u[0] = E0; f[0].u[1] = E1; f[0].u[2] = F0; f[0].u[3] = F1;
    unsigned G0 = packbf(P[8],  P[9]),  G1 = packbf(P[10], P[11]);
    unsigned H0 = packbf(P[12], P[13]), H1 = packbf(P[14], P[15]);
    plswap(G0, H0); plswap(G1, H1);
    f[1].u[0] = G0; f[1].u[1] = G1; f[1].u[2] = H0; f[1].u[3] = H1;
}

// ---------------------------------------------------------------------------
// Prep A (mfma): Kh f16 [n][84] = x@Wk^T+bk (cols 66..83 = 0);
//                Xb bf16 blocked [n/32][96][36], row 66 = ones.
// 512 blocks x 256 thr; block = 128 x-rows; 18 mfma/wave.
// ---------------------------------------------------------------------------
#define PA_ROWS 128
__global__ __launch_bounds__(256) void prepA_kernel(
    const float* __restrict__ x, const float* __restrict__ Wk,
    const float* __restrict__ bk,
    unsigned short* __restrict__ Kh_u, unsigned short* __restrict__ Xb_u) {
    _Float16* Kh = (_Float16*)Kh_u;
    __bf16*   Xb = (__bf16*)Xb_u;
    __shared__ _Float16 sxh[PA_ROWS * 96];   // 24576 B, x rows in f16, k-padded
    __shared__ _Float16 sW[96 * 96];         // 18432 B, Wk rows in f16, padded
    const int tid = threadIdx.x;
    const long n0 = (long)blockIdx.x * PA_ROWS;

    for (int i = tid; i < PA_ROWS * 96; i += 256) {
        int r = i / 96, c = i % 96;
        float v = (c < DIM) ? x[(n0 + r) * DIM + c] : 0.f;
        sxh[i] = (_Float16)v;
    }
    for (int i = tid; i < 96 * 96; i += 256) {
        int cc = i / 96, d = i % 96;
        float v = (cc < DIM && d < DIM) ? Wk[cc * DIM + d] : 0.f;
        sW[i] = (_Float16)v;
    }
    __syncthreads();

    const int lane = tid & 63, w = tid >> 6;
    const int l31 = lane & 31, h = lane >> 5;

    #pragma unroll
    for (int nt = 0; nt < 3; ++nt) {
        f32x16 acc = {};
        #pragma unroll
        for (int kk = 0; kk < 6; ++kk) {
            f16x8 a = *(const f16x8*)&sxh[(w * 32 + l31) * 96 + kk * 16 + h * 8];
            f16x8 b = *(const f16x8*)&sW[(nt * 32 + l31) * 96 + kk * 16 + h * 8];
            acc = mfma_f16(a, b, acc);
        }
        int c = nt * 32 + l31;
        float bkv = (c < DIM) ? bk[c] : 0.f;   // cols 66..83: acc==0, bkv==0 -> stores 0
        if (c < KPITCH) {
            #pragma unroll
            for (int r = 0; r < 16; ++r) {
                int row = (r & 3) + 8 * (r >> 2) + 4 * h;
                Kh[(n0 + w * 32 + row) * KPITCH + c] = (_Float16)(acc[r] + bkv);
            }
        }
    }

    // X transpose -> Xb bf16 (4 pair-blocks of 32)
    for (int ii = tid; ii < 4 * XTILE; ii += 256) {
        int b = ii / XTILE, i = ii % XTILE;
        int dd = i / XPITCH, j = i % XPITCH;
        float v = 0.f;
        if (j < 32) {
            if (dd < DIM) v = (float)sxh[(b * 32 + j) * 96 + dd];
            else if (dd == DIM) v = 1.f;
        }
        Xb[((long)blockIdx.x * 4 + b) * XTILE + i] = (__bf16)v;
    }
}

// ---------------------------------------------------------------------------
// Prep B: Qh f16 [q][80] = query * log2(e), k-padded with 0
// ---------------------------------------------------------------------------
__global__ __launch_bounds__(256) void prepB_kernel(
    const float* __restrict__ query, unsigned short* __restrict__ Qh_u) {
    _Float16* Qh = (_Float16*)Qh_u;
    int idx = blockIdx.x * 256 + threadIdx.x;       // < 8192*80
    int q = idx / QPITCH, c = idx % QPITCH;
    float v = (c < DIM) ? query[(long)q * DIM + c] * 1.4426950408889634f : 0.f;
    Qh[idx] = (_Float16)v;
}

// ---------------------------------------------------------------------------
// Flash: grid = 32 qblocks * NS chunks; 256 thr = 4 waves; 64 queries/wave.
// Per 64-pair tile: Sᵀ = K·Qᵀ (f16 mfma), P = exp2(Sᵀ) in-register,
// permlane32_swap -> PV A-frags, O += P·[X|1] (bf16 mfma). No P in LDS.
// ---------------------------------------------------------------------------
__global__ __launch_bounds__(256, 2) void flash_kernel(
    const unsigned short* __restrict__ Qh_u, const unsigned short* __restrict__ Kh_u,
    const unsigned short* __restrict__ Xb_u, float* __restrict__ Part, int NS) {
    __shared__ __attribute__((aligned(16))) char smem[LDS_TOTAL];
    _Float16* Kt = (_Float16*)(smem + LDS_KT);
    __bf16*   Xt = (__bf16*)(smem + LDS_XT);
    const _Float16* Qh = (const _Float16*)Qh_u;
    const _Float16* Kh = (const _Float16*)Kh_u;

    const int tid = threadIdx.x;
    const int lane = tid & 63, wave = tid >> 6;
    const int l31 = lane & 31, h = lane >> 5;
    const int qb = blockIdx.x / NS, ns = blockIdx.x % NS;
    const int ppc = NUM_PAIRS / NS;
    const int iters = ppc >> 6;
    const int qbase = qb * 256 + wave * 64;

    // Q frags (B-operand of Sᵀ: lane holds Q[q=qt*32+l31][k=8h+j]) — persistent
    f16x8 aQ[2][5];
    #pragma unroll
    for (int qt = 0; qt < 2; ++qt)
        #pragma unroll
        for (int kk = 0; kk < 5; ++kk)
            aQ[qt][kk] = *(const f16x8*)&Qh[(long)(qbase + qt * 32 + l31) * QPITCH + kk * 16 + h * 8];

    f32x16 o[2][3] = {};   // O acc: [qt][dtile], C-layout col=d, row=query

    for (int it = 0; it < iters; ++it) {
        const long p0 = (long)ns * ppc + (long)it * 64;
        __syncthreads();                       // prev-iter LDS reads done
        {   // stage Kt (10752B) + Xt (13824B) = 24 x 1KB chunks
            const char* gK = (const char*)(Kh + p0 * KPITCH);
            const char* gX = (const char*)(Xb_u + (p0 >> 5) * XTILE);
            for (int c = wave; c < 24; c += 4) {
                int off = c * 1024 + lane * 16;
                const char* src = (off < 10752) ? (gK + off) : (gX + (off - 10752));
                __builtin_amdgcn_global_load_lds(
                    (const __attribute__((address_space(1))) void*)(uintptr_t)src,
                    (__attribute__((address_space(3))) void*)(unsigned int)(uintptr_t)(smem + c * 1024),
                    16, 0, 0);
            }
        }
        __syncthreads();                       // staged tiles visible

        #pragma unroll
        for (int pt = 0; pt < 2; ++pt) {
            // Sᵀ[pair pt*32+m][query qt*32+n] : A = K-frag, B = Q-frag
            f16x8 bK[5];
            #pragma unroll
            for (int kk = 0; kk < 5; ++kk)
                bK[kk] = frag8h(&Kt[(pt * 32 + l31) * KPITCH + kk * 16 + h * 8]);
            f32x16 s0 = {}, s1 = {};
            #pragma unroll
            for (int kk = 0; kk < 5; ++kk) {
                s0 = mfma_f16(bK[kk], aQ[0][kk], s0);
                s1 = mfma_f16(bK[kk], aQ[1][kk], s1);
            }
            U4 f[2][2];                        // [qt][parity]
            makefrags(s0, f[0]);
            makefrags(s1, f[1]);
            #pragma unroll
            for (int par = 0; par < 2; ++par) {
                const int kc = par * 16 + h * 8;
                #pragma unroll
                for (int dt = 0; dt < 3; ++dt) {
                    bf16x8 bX = frag8(&Xt[pt * XTILE + (dt * 32 + l31) * XPITCH + kc]);
                    o[0][dt] = mfma_bf16(f[0][par].v, bX, o[0][dt]);
                    o[1][dt] = mfma_bf16(f[1][par].v, bX, o[1][dt]);
                }
            }
        }
    }

    // epilogue: unnormalized partials; col 66 = sum(exp) denominator
    float* dst = Part + (long)ns * NUM_Q * PARTP;
    #pragma unroll
    for (int qt = 0; qt < 2; ++qt)
        #pragma unroll
        for (int dt = 0; dt < 3; ++dt)
            #pragma unroll
            for (int r = 0; r < 16; ++r) {
                int row = (r & 3) + 8 * (r >> 2) + 4 * h;
                int q = qbase + qt * 32 + row;
                int d = dt * 32 + l31;
                if (d < DIM + 1) dst[(long)q * PARTP + d] = o[qt][dt][r];
            }
}

// ---------------------------------------------------------------------------
// Combine: out[q][d] = sum_ns Part[ns][q][d] / sum_ns Part[ns][q][66]
// ---------------------------------------------------------------------------
__global__ __launch_bounds__(256) void combine_kernel(
    const float* __restrict__ Part, float* __restrict__ out, int NS) {
    int q = blockIdx.x * 2 + (threadIdx.x >> 7);
    int d = threadIdx.x & 127;
    if (d >= DIM) return;
    float num = 0.f, den = 0.f;
    for (int s = 0; s < NS; ++s) {
        const float* p = Part + ((long)s * NUM_Q + q) * PARTP;
        num += p[d];
        den += p[DIM];
    }
    out[(long)q * DIM + d] = num / den;
}

// ---------------------------------------------------------------------------
// Workspace: Qh @0 (1,310,720 B) ; Kh @1310720 (11,010,048 B) ;
//            Xb @12320768 (14,155,776 B) ; Part @26476544 (NS*8192*68*4 B)
// ---------------------------------------------------------------------------
extern "C" void kernel_launch(void* const* d_in, const int* in_sizes, int n_in,
                              void* d_out, int out_size, void* d_ws, size_t ws_size,
                              hipStream_t stream) {
    const float* x     = (const float*)d_in[0];
    const float* query = (const float*)d_in[1];
    const float* Wk    = (const float*)d_in[2];
    const float* bk    = (const float*)d_in[3];
    float* out = (float*)d_out;
    char* ws = (char*)d_ws;

    unsigned short* Qh = (unsigned short*)(ws + 0);
    unsigned short* Kh = (unsigned short*)(ws + 1310720);
    unsigned short* Xb = (unsigned short*)(ws + 12320768);
    float* Part        = (float*)(ws + 26476544);

    int NS = 16;
    while (NS > 1 &&
           26476544ULL + (unsigned long long)NS * NUM_Q * PARTP * 4ULL > (unsigned long long)ws_size)
        NS >>= 1;

    prepA_kernel<<<NUM_PAIRS / PA_ROWS, 256, 0, stream>>>(x, Wk, bk, Kh, Xb);
    prepB_kernel<<<(NUM_Q * QPITCH) / 256, 256, 0, stream>>>(query, Qh);
    flash_kernel<<<(NUM_Q / 256) * NS, 256, 0, stream>>>(Qh, Kh, Xb, Part, NS);
    combine_kernel<<<NUM_Q / 2, 256, 0, stream>>>(Part, out, NS);
}

// Round 3
// 289.611 us; speedup vs baseline: 1.0807x; 1.0039x over previous
//
#include <hip/hip_runtime.h>
#include <cstdint>

// ---------------------------------------------------------------------------
// AttentionSelector: selected = softmax(query @ (x@Wk^T+bk)^T) @ x
// R3: (a) double-buffered global_load_lds staging with TWO distinct __shared__
//     arrays + K-loop unrolled by 2 (compile-time buffer binding so alias
//     analysis can't serialize stage vs ds_read). Stage of tile i+1 issues
//     right after the barrier; its vmcnt drain lands one compute-phase later.
//     (b) prepA LDS pitch 96->104 (16-way bank conflict -> 4-way).
// ---------------------------------------------------------------------------

typedef __bf16    bf16x4 __attribute__((ext_vector_type(4)));
typedef __bf16    bf16x8 __attribute__((ext_vector_type(8)));
typedef _Float16  f16x4  __attribute__((ext_vector_type(4)));
typedef _Float16  f16x8  __attribute__((ext_vector_type(8)));
typedef float     f32x16 __attribute__((ext_vector_type(16)));

extern "C" __device__ float __ocml_native_exp2_f32(float);

#define NUM_PAIRS   65536
#define NUM_Q       8192
#define DIM         66
#define KPITCH      84      // Kh row pitch (f16): 168B rows, 2-way-free b64 reads
#define QPITCH      80      // Qh row pitch (f16)
#define XROWS       96      // xT rows: 0..65 data, 66 ones, 67..95 zero
#define XPITCH      36      // xT tile col pitch (72B rows, 2-way free)
#define XTILE       (XROWS*XPITCH)   // 3456 elems / 6912 B per 32-pair block
#define PARTP       68      // partial row pitch (floats)

// staged tile (bytes): Kt [64][84] f16 = 10752 @0 ; Xt [2][96][36] bf16 = 13824 @10752
#define LDS_XT 10752
#define STG    24576        // 24 x 1KB chunks per tile
#define KSTRIDE 10752       // bytes of Kh per 64-pair tile
#define XSTRIDE 13824       // bytes of Xb per 64-pair tile

__device__ __forceinline__ bf16x8 frag8(const __bf16* p) {
    bf16x4 lo = *(const bf16x4*)p;
    bf16x4 hi = *(const bf16x4*)(p + 4);
    return __builtin_shufflevector(lo, hi, 0, 1, 2, 3, 4, 5, 6, 7);
}
__device__ __forceinline__ f16x8 frag8h(const _Float16* p) {
    f16x4 lo = *(const f16x4*)p;
    f16x4 hi = *(const f16x4*)(p + 4);
    return __builtin_shufflevector(lo, hi, 0, 1, 2, 3, 4, 5, 6, 7);
}
__device__ __forceinline__ f32x16 mfma_bf16(bf16x8 a, bf16x8 b, f32x16 c) {
    return __builtin_amdgcn_mfma_f32_32x32x16_bf16(a, b, c, 0, 0, 0);
}
__device__ __forceinline__ f32x16 mfma_f16(f16x8 a, f16x8 b, f32x16 c) {
    return __builtin_amdgcn_mfma_f32_32x32x16_f16(a, b, c, 0, 0, 0);
}

// gfx950: exchange lanes 32..63 of a with lanes 0..31 of b.
__device__ __forceinline__ void plswap(unsigned &a, unsigned &b) {
    asm("v_permlane32_swap_b32 %0, %1" : "+v"(a), "+v"(b));
}
__device__ __forceinline__ unsigned packbf(float a, float b) {
    union { __bf16 h[2]; unsigned u; } t;
    t.h[0] = (__bf16)a; t.h[1] = (__bf16)b;
    return t.u;
}

union U4 { unsigned u[4]; bf16x8 v; };

// Sᵀ C-tile (col=query l31, row(pair)=(r&3)+8*(r>>2)+4h) -> exp2 -> two PV
// A-frags via permlane32_swap (verified R2).
__device__ __forceinline__ void makefrags(const f32x16 &s, U4 *f) {
    float P[16];
    #pragma unroll
    for (int r = 0; r < 16; ++r) P[r] = __ocml_native_exp2_f32(s[r]);
    unsigned E0 = packbf(P[0],  P[1]),  E1 = packbf(P[2],  P[3]);
    unsigned F0 = packbf(P[4],  P[5]),  F1 = packbf(P[6],  P[7]);
    plswap(E0, F0); plswap(E1, F1);
    f[0].u[0] = E0; f[0].u[1] = E1; f[0].u[2] = F0; f[0].u[3] = F1;
    unsigned G0 = packbf(P[8],  P[9]),  G1 = packbf(P[10], P[11]);
    unsigned H0 = packbf(P[12], P[13]), H1 = packbf(P[14], P[15]);
    plswap(G0, H0); plswap(G1, H1);
    f[1].u[0] = G0; f[1].u[1] = G1; f[1].u[2] = H0; f[1].u[3] = H1;
}

__device__ __forceinline__ void stage_tile(char* dst, const char* gK, const char* gX,
                                           int wave, int lane) {
    #pragma unroll
    for (int j = 0; j < 6; ++j) {
        int c = wave + 4 * j;
        int off = c * 1024 + lane * 16;
        const char* src = (off < KSTRIDE) ? (gK + off) : (gX + (off - KSTRIDE));
        __builtin_amdgcn_global_load_lds(
            (const __attribute__((address_space(1))) void*)(uintptr_t)src,
            (__attribute__((address_space(3))) void*)(unsigned int)(uintptr_t)(dst + c * 1024),
            16, 0, 0);
    }
}

__device__ __forceinline__ void compute_tile(const char* sm, const f16x8 (&aQ)[2][5],
                                             f32x16 (&o)[2][3], int l31, int h) {
    const _Float16* Kt = (const _Float16*)sm;
    const __bf16*   Xt = (const __bf16*)(sm + LDS_XT);
    #pragma unroll
    for (int pt = 0; pt < 2; ++pt) {
        f16x8 bK[5];
        #pragma unroll
        for (int kk = 0; kk < 5; ++kk)
            bK[kk] = frag8h(&Kt[(pt * 32 + l31) * KPITCH + kk * 16 + h * 8]);
        f32x16 s0 = {}, s1 = {};
        #pragma unroll
        for (int kk = 0; kk < 5; ++kk) {
            s0 = mfma_f16(bK[kk], aQ[0][kk], s0);
            s1 = mfma_f16(bK[kk], aQ[1][kk], s1);
        }
        U4 f[2][2];
        makefrags(s0, f[0]);
        makefrags(s1, f[1]);
        #pragma unroll
        for (int par = 0; par < 2; ++par) {
            const int kc = par * 16 + h * 8;
            #pragma unroll
            for (int dt = 0; dt < 3; ++dt) {
                bf16x8 bX = frag8(&Xt[pt * XTILE + (dt * 32 + l31) * XPITCH + kc]);
                o[0][dt] = mfma_bf16(f[0][par].v, bX, o[0][dt]);
                o[1][dt] = mfma_bf16(f[1][par].v, bX, o[1][dt]);
            }
        }
    }
}

// ---------------------------------------------------------------------------
// Prep A (mfma f16): Kh [n][84] = x@Wk^T+bk ; Xb bf16 blocked [n/32][96][36].
// LDS pitch 104 f16 (208B): A/B frag reads 4-way instead of 16-way conflicted.
// ---------------------------------------------------------------------------
#define PA_ROWS 128
#define PAP 104
__global__ __launch_bounds__(256) void prepA_kernel(
    const float* __restrict__ x, const float* __restrict__ Wk,
    const float* __restrict__ bk,
    unsigned short* __restrict__ Kh_u, unsigned short* __restrict__ Xb_u) {
    _Float16* Kh = (_Float16*)Kh_u;
    __bf16*   Xb = (__bf16*)Xb_u;
    __shared__ _Float16 sxh[PA_ROWS * PAP];
    __shared__ _Float16 sW[96 * PAP];
    const int tid = threadIdx.x;
    const long n0 = (long)blockIdx.x * PA_ROWS;

    for (int i = tid; i < PA_ROWS * 96; i += 256) {
        int r = i / 96, c = i % 96;
        sxh[r * PAP + c] = (_Float16)((c < DIM) ? x[(n0 + r) * DIM + c] : 0.f);
    }
    for (int i = tid; i < 96 * 96; i += 256) {
        int cc = i / 96, d = i % 96;
        sW[cc * PAP + d] = (_Float16)((cc < DIM && d < DIM) ? Wk[cc * DIM + d] : 0.f);
    }
    __syncthreads();

    const int lane = tid & 63, w = tid >> 6;
    const int l31 = lane & 31, h = lane >> 5;

    #pragma unroll
    for (int nt = 0; nt < 3; ++nt) {
        f32x16 acc = {};
        #pragma unroll
        for (int kk = 0; kk < 6; ++kk) {
            f16x8 a = *(const f16x8*)&sxh[(w * 32 + l31) * PAP + kk * 16 + h * 8];
            f16x8 b = *(const f16x8*)&sW[(nt * 32 + l31) * PAP + kk * 16 + h * 8];
            acc = mfma_f16(a, b, acc);
        }
        int c = nt * 32 + l31;
        float bkv = (c < DIM) ? bk[c] : 0.f;
        if (c < KPITCH) {
            #pragma unroll
            for (int r = 0; r < 16; ++r) {
                int row = (r & 3) + 8 * (r >> 2) + 4 * h;
                Kh[(n0 + w * 32 + row) * KPITCH + c] = (_Float16)(acc[r] + bkv);
            }
        }
    }

    for (int ii = tid; ii < 4 * XTILE; ii += 256) {
        int b = ii / XTILE, i = ii % XTILE;
        int dd = i / XPITCH, j = i % XPITCH;
        float v = 0.f;
        if (j < 32) {
            if (dd < DIM) v = (float)sxh[(b * 32 + j) * PAP + dd];
            else if (dd == DIM) v = 1.f;
        }
        Xb[((long)blockIdx.x * 4 + b) * XTILE + i] = (__bf16)v;
    }
}

// ---------------------------------------------------------------------------
// Prep B: Qh f16 [q][80] = query * log2(e), k-padded with 0
// ---------------------------------------------------------------------------
__global__ __launch_bounds__(256) void prepB_kernel(
    const float* __restrict__ query, unsigned short* __restrict__ Qh_u) {
    _Float16* Qh = (_Float16*)Qh_u;
    int idx = blockIdx.x * 256 + threadIdx.x;
    int q = idx / QPITCH, c = idx % QPITCH;
    float v = (c < DIM) ? query[(long)q * DIM + c] * 1.4426950408889634f : 0.f;
    Qh[idx] = (_Float16)v;
}

// ---------------------------------------------------------------------------
// Flash: grid = 32 qblocks * NS chunks; 256 thr = 4 waves; 64 q/wave.
// Double-buffered: stage tile i+1 into the other buffer right after the
// barrier, compute tile i; drain for i+1 happens at the NEXT barrier.
// ---------------------------------------------------------------------------
__global__ __launch_bounds__(256, 2) void flash_kernel(
    const unsigned short* __restrict__ Qh_u, const unsigned short* __restrict__ Kh_u,
    const unsigned short* __restrict__ Xb_u, float* __restrict__ Part, int NS) {
    __shared__ __attribute__((aligned(16))) char smA[STG];
    __shared__ __attribute__((aligned(16))) char smB[STG];
    const _Float16* Qh = (const _Float16*)Qh_u;

    const int tid = threadIdx.x;
    const int lane = tid & 63, wave = tid >> 6;
    const int l31 = lane & 31, h = lane >> 5;
    const int qb = blockIdx.x / NS, ns = blockIdx.x % NS;
    const int ppc = NUM_PAIRS / NS;
    const int iters = ppc >> 6;              // even for all NS in {1..16}
    const int qbase = qb * 256 + wave * 64;

    const long pbase = (long)ns * ppc;
    const char* gK0 = (const char*)Kh_u + pbase * (KPITCH * 2);
    const char* gX0 = (const char*)Xb_u + (pbase >> 5) * (XTILE * 2);

    f16x8 aQ[2][5];
    #pragma unroll
    for (int qt = 0; qt < 2; ++qt)
        #pragma unroll
        for (int kk = 0; kk < 5; ++kk)
            aQ[qt][kk] = *(const f16x8*)&Qh[(long)(qbase + qt * 32 + l31) * QPITCH + kk * 16 + h * 8];

    f32x16 o[2][3] = {};

    stage_tile(smA, gK0, gX0, wave, lane);
    for (int it = 0; it < iters; it += 2) {
        __syncthreads();   // tile it ready in A; everyone done reading B
        if (it + 1 < iters)
            stage_tile(smB, gK0 + (long)(it + 1) * KSTRIDE,
                            gX0 + (long)(it + 1) * XSTRIDE, wave, lane);
        compute_tile(smA, aQ, o, l31, h);
        __syncthreads();   // tile it+1 ready in B; everyone done reading A
        if (it + 2 < iters)
            stage_tile(smA, gK0 + (long)(it + 2) * KSTRIDE,
                            gX0 + (long)(it + 2) * XSTRIDE, wave, lane);
        compute_tile(smB, aQ, o, l31, h);
    }

    // epilogue: unnormalized partials; col 66 = sum(exp) denominator
    float* dst = Part + (long)ns * NUM_Q * PARTP;
    #pragma unroll
    for (int qt = 0; qt < 2; ++qt)
        #pragma unroll
        for (int dt = 0; dt < 3; ++dt)
            #pragma unroll
            for (int r = 0; r < 16; ++r) {
                int row = (r & 3) + 8 * (r >> 2) + 4 * h;
                int q = qbase + qt * 32 + row;
                int d = dt * 32 + l31;
                if (d < DIM + 1) dst[(long)q * PARTP + d] = o[qt][dt][r];
            }
}

// ---------------------------------------------------------------------------
// Combine: out[q][d] = sum_ns Part[ns][q][d] / sum_ns Part[ns][q][66]
// ---------------------------------------------------------------------------
__global__ __launch_bounds__(256) void combine_kernel(
    const float* __restrict__ Part, float* __restrict__ out, int NS) {
    int q = blockIdx.x * 2 + (threadIdx.x >> 7);
    int d = threadIdx.x & 127;
    if (d >= DIM) return;
    float num = 0.f, den = 0.f;
    #pragma unroll 4
    for (int s = 0; s < NS; ++s) {
        const float* p = Part + ((long)s * NUM_Q + q) * PARTP;
        num += p[d];
        den += p[DIM];
    }
    out[(long)q * DIM + d] = num / den;
}

// ---------------------------------------------------------------------------
// Workspace: Qh @0 (1,310,720 B) ; Kh @1310720 (11,010,048 B) ;
//            Xb @12320768 (14,155,776 B) ; Part @26476544 (NS*8192*68*4 B)
// ---------------------------------------------------------------------------
extern "C" void kernel_launch(void* const* d_in, const int* in_sizes, int n_in,
                              void* d_out, int out_size, void* d_ws, size_t ws_size,
                              hipStream_t stream) {
    const float* x     = (const float*)d_in[0];
    const float* query = (const float*)d_in[1];
    const float* Wk    = (const float*)d_in[2];
    const float* bk    = (const float*)d_in[3];
    float* out = (float*)d_out;
    char* ws = (char*)d_ws;

    unsigned short* Qh = (unsigned short*)(ws + 0);
    unsigned short* Kh = (unsigned short*)(ws + 1310720);
    unsigned short* Xb = (unsigned short*)(ws + 12320768);
    float* Part        = (float*)(ws + 26476544);

    int NS = 16;
    while (NS > 1 &&
           26476544ULL + (unsigned long long)NS * NUM_Q * PARTP * 4ULL > (unsigned long long)ws_size)
        NS >>= 1;

    prepA_kernel<<<NUM_PAIRS / PA_ROWS, 256, 0, stream>>>(x, Wk, bk, Kh, Xb);
    prepB_kernel<<<(NUM_Q * QPITCH) / 256, 256, 0, stream>>>(query, Qh);
    flash_kernel<<<(NUM_Q / 256) * NS, 256, 0, stream>>>(Qh, Kh, Xb, Part, NS);
    combine_kernel<<<NUM_Q / 2, 256, 0, stream>>>(Part, out, NS);
}